// Round 1
// baseline (2777.918 us; speedup 1.0000x reference)
//
#include <hip/hip_runtime.h>
#include <hip/hip_cooperative_groups.h>
#include <stdint.h>

namespace cg = cooperative_groups;

#define N_NODES    50000
#define K_MAX      10
#define BATCH      64
#define T_STEPS    32
#define N_INPUTS   16
#define INPUT_BITS 64

#define NODES_PER_WG 256
#define MAIN_WGS     196     // ceil(50000/256)
#define MAIN_THREADS 1024

static const size_t BUF_BYTES_AL = 400064;  // uint64[50001] padded to 64B

// ---------------- prep: init transposed state + per-step xor masks ----------------
__global__ void prep_kernel(const int* __restrict__ x,
                            const int* __restrict__ init_states,
                            const int* __restrict__ input_nodes,
                            uint64_t* __restrict__ buf0,
                            uint64_t* __restrict__ buf1,
                            uint64_t* __restrict__ xmask) {
    int gid = blockIdx.x * blockDim.x + threadIdx.x;
    if (gid < N_NODES + 1) {
        int n = gid;
        if (n == N_NODES) { buf0[n] = 0ull; buf1[n] = 0ull; return; }  // zero sentinel
        // last occurrence of n in input_nodes (last-write-wins scatter semantics)
        int jm = -1;
        for (int j = 0; j < INPUT_BITS; ++j)
            if (input_nodes[j] == n) jm = j;
        uint64_t v = init_states[n] ? ~0ull : 0ull;   // same init for all 64 batches
        if (jm >= 0) {
            uint64_t m = 0ull;
            for (int b = 0; b < BATCH; ++b)
                m |= (uint64_t)(x[b * (T_STEPS * INPUT_BITS) + jm] & 1) << b;  // t = 0
            v ^= m;
        }
        buf0[n] = v;
    } else {
        int k = gid - (N_NODES + 1);
        if (k < T_STEPS * INPUT_BITS) {
            int t = k >> 6, j = k & 63;
            uint64_t m = 0ull;
            for (int b = 0; b < BATCH; ++b)
                m |= (uint64_t)(x[b * (T_STEPS * INPUT_BITS) + t * INPUT_BITS + j] & 1) << b;
            xmask[k] = m;
        }
    }
}

// ---------------- main cooperative time-loop kernel ----------------
__global__ __launch_bounds__(MAIN_THREADS)
void reservoir_kernel(const int* __restrict__ adj,
                      const int* __restrict__ adjmask,
                      const int* __restrict__ lut,
                      const int* __restrict__ input_nodes,
                      const uint64_t* __restrict__ xmask,
                      uint64_t* __restrict__ buf0,
                      uint64_t* __restrict__ buf1) {
    __shared__ uint8_t lutb[NODES_PER_WG * 128];   // 32 KB: packed LUT rows, static over steps

    const int tid  = threadIdx.x;
    const int lane = tid & 63;
    const int wave = tid >> 6;
    const int wg   = blockIdx.x;

    // Stage this WG's 256 LUT rows, bit-packed, via coalesced load + ballot.
    for (int r = wave; r < NODES_PER_WG; r += 16) {
        int gn = wg * NODES_PER_WG + r;
        if (gn < N_NODES) {
            #pragma unroll
            for (int c = 0; c < 16; ++c) {
                int v = lut[(size_t)gn * 1024 + (size_t)c * 64 + lane];
                uint64_t m = __ballot(v & 1);
                if (lane == 0) *(uint64_t*)(lutb + r * 128 + c * 8) = m;
            }
        }
    }
    __syncthreads();

    const int nl   = tid >> 2;                    // local node within WG
    const int q    = tid & 3;                     // batch quarter (16 batches)
    const int node = wg * NODES_PER_WG + nl;
    const bool valid = node < N_NODES;

    int jm = -1;
    uint32_t adjoff[K_MAX];
    if (valid) {
        for (int j = 0; j < INPUT_BITS; ++j)
            if (input_nodes[j] == node) jm = j;   // last occurrence
        #pragma unroll
        for (int k = 0; k < K_MAX; ++k) {
            int a  = adj[node * K_MAX + k];
            int mk = adjmask[node * K_MAX + k];
            // masked-off neighbor -> sentinel word 50000 which stays 0 forever
            adjoff[k] = (uint32_t)(mk ? a : N_NODES) * 8u + (uint32_t)q * 2u;
        }
    }
    const int rowbase = nl * 128;

    uint64_t* bufs[2] = { buf0, buf1 };
    cg::grid_group grid = cg::this_grid();

    for (int t = 0; t < T_STEPS; ++t) {
        if (valid) {
            const char* src = (const char*)bufs[t & 1];
            uint32_t w[K_MAX];
            #pragma unroll
            for (int k = 0; k < K_MAX; ++k)
                w[k] = *(const uint16_t*)(src + adjoff[k]);

            uint32_t o16 = 0;
            #pragma unroll
            for (int b = 0; b < 16; ++b) {
                uint32_t idx = 0;
                #pragma unroll
                for (int k = 0; k < K_MAX; ++k)
                    idx |= ((w[k] >> b) & 1u) << (9 - k);       // pow2[k] = 2^(9-k)
                uint32_t byte = lutb[rowbase + (idx >> 3)];
                o16 |= ((byte >> (idx & 7)) & 1u) << b;
            }
            // fold next step's input-bit XOR into this write (no extra grid sync)
            if (jm >= 0 && t < T_STEPS - 1)
                o16 ^= (uint32_t)((xmask[(t + 1) * INPUT_BITS + jm] >> (q * 16)) & 0xFFFFu);

            ((uint16_t*)bufs[(t + 1) & 1])[(size_t)node * 4 + q] = (uint16_t)o16;
        }
        __threadfence();
        grid.sync();
    }
}

// ---------------- output: out[b,i] = sum_n state[b,n]*W[i,n] + bias[i] ----------------
__global__ void out_kernel(const uint64_t* __restrict__ fstate,
                           const float* __restrict__ W,
                           const float* __restrict__ bias,
                           float* __restrict__ out) {
    const int wg = blockIdx.x;          // b*16 + i
    const int b = wg >> 4, i = wg & 15;
    const int tid = threadIdx.x;
    const uint8_t* st = (const uint8_t*)fstate;
    const int byteoff = b >> 3, bsh = b & 7;

    float s = 0.f;
    for (int n = tid; n < N_NODES; n += 256) {
        uint32_t bit = (st[(size_t)n * 8 + byteoff] >> bsh) & 1u;
        s += (float)bit * W[(size_t)i * N_NODES + n];
    }
    #pragma unroll
    for (int off = 32; off; off >>= 1) s += __shfl_down(s, off);

    __shared__ float part[4];
    const int lane = tid & 63, wave = tid >> 6;
    if (lane == 0) part[wave] = s;
    __syncthreads();
    if (tid == 0) out[wg] = part[0] + part[1] + part[2] + part[3] + bias[i];
}

extern "C" void kernel_launch(void* const* d_in, const int* in_sizes, int n_in,
                              void* d_out, int out_size, void* d_ws, size_t ws_size,
                              hipStream_t stream) {
    const int*   x       = (const int*)d_in[0];
    const int*   adj     = (const int*)d_in[1];
    const int*   adjmask = (const int*)d_in[2];
    const int*   lut     = (const int*)d_in[3];
    const int*   initst  = (const int*)d_in[4];
    const int*   innodes = (const int*)d_in[5];
    const float* W       = (const float*)d_in[6];
    const float* bias    = (const float*)d_in[7];
    float* out = (float*)d_out;

    char* ws = (char*)d_ws;
    uint64_t* buf0  = (uint64_t*)(ws);
    uint64_t* buf1  = (uint64_t*)(ws + BUF_BYTES_AL);
    uint64_t* xmask = (uint64_t*)(ws + 2 * BUF_BYTES_AL);

    {
        int prep_threads = (N_NODES + 1) + T_STEPS * INPUT_BITS;
        int prep_blocks = (prep_threads + 255) / 256;
        hipLaunchKernelGGL(prep_kernel, dim3(prep_blocks), dim3(256), 0, stream,
                           x, initst, innodes, buf0, buf1, xmask);
    }

    {
        void* args[] = { (void*)&adj, (void*)&adjmask, (void*)&lut, (void*)&innodes,
                         (void*)&xmask, (void*)&buf0, (void*)&buf1 };
        hipLaunchCooperativeKernel((void*)reservoir_kernel,
                                   dim3(MAIN_WGS), dim3(MAIN_THREADS),
                                   args, 0, stream);
    }

    // after 32 steps the final states live in buf0 (32 is even)
    hipLaunchKernelGGL(out_kernel, dim3(BATCH * N_INPUTS), dim3(256), 0, stream,
                       (const uint64_t*)buf0, W, bias, out);
}

// Round 2
// 333.623 us; speedup vs baseline: 8.3265x; 8.3265x over previous
//
#include <hip/hip_runtime.h>
#include <stdint.h>

#define N_NODES    50000
#define K_MAX      10
#define BATCH      64
#define T_STEPS    32
#define N_INPUTS   16
#define INPUT_BITS 64

// ---------------- workspace layout (bytes) ----------------
#define OFF_BUF0   0u          // uint64[50001] state ping
#define OFF_BUF1   400128u     // uint64[50001] state pong
#define OFF_XMASK  800256u     // uint64[32*64] per-step input xor masks
#define OFF_JM     816640u     // int32[50000] last input-bit index per node (-1 none)
#define OFF_ADJ    1016640u    // int32[10][50000] byte offsets into state buf (sentinel-resolved)
#define OFF_PLUT   3016640u    // uint8[50000*128] bit-packed LUT
// total ~9.42 MB

#define STEP_THREADS 256
#define NODES_PER_WG 64
#define STEP_WGS ((N_NODES + NODES_PER_WG - 1) / NODES_PER_WG)   // 782

// ---------------- prep: xor masks, per-node metadata, init state ----------------
__global__ void prep_kernel(const int* __restrict__ x,
                            const int* __restrict__ adj,
                            const int* __restrict__ adjmask,
                            const int* __restrict__ init_states,
                            const int* __restrict__ input_nodes,
                            uint64_t* __restrict__ buf0,
                            uint64_t* __restrict__ buf1,
                            uint64_t* __restrict__ xmask,
                            int* __restrict__ jmv,
                            int* __restrict__ adjoffT) {
    int gid = blockIdx.x * blockDim.x + threadIdx.x;
    if (gid < N_NODES) {
        int n = gid;
        // last occurrence of n in input_nodes (last-write-wins scatter semantics)
        int jm = -1;
        for (int j = 0; j < INPUT_BITS; ++j)
            if (input_nodes[j] == n) jm = j;
        jmv[n] = jm;
        #pragma unroll
        for (int k = 0; k < K_MAX; ++k) {
            int a  = adj[n * K_MAX + k];
            int mk = adjmask[n * K_MAX + k];
            // masked-off neighbor -> sentinel word N_NODES which stays 0 forever
            adjoffT[k * N_NODES + n] = (mk ? a : N_NODES) * 8;
        }
        uint64_t v = init_states[n] ? ~0ull : 0ull;   // same init for all 64 batches
        if (jm >= 0) {
            uint64_t m = 0ull;
            for (int b = 0; b < BATCH; ++b)
                m |= (uint64_t)(x[b * (T_STEPS * INPUT_BITS) + jm] & 1) << b;  // t = 0
            v ^= m;
        }
        buf0[n] = v;
    } else if (gid == N_NODES) {
        buf0[N_NODES] = 0ull; buf1[N_NODES] = 0ull;   // zero sentinel
    } else {
        int k = gid - (N_NODES + 1);
        if (k < T_STEPS * INPUT_BITS) {
            int t = k >> 6, j = k & 63;
            uint64_t m = 0ull;
            for (int b = 0; b < BATCH; ++b)
                m |= (uint64_t)(x[b * (T_STEPS * INPUT_BITS) + t * INPUT_BITS + j] & 1) << b;
            xmask[k] = m;
        }
    }
}

// ---------------- pack LUT to bits: 204.8 MB int32 -> 6.4 MB ----------------
__global__ void lutpack_kernel(const int* __restrict__ lut,
                               uint64_t* __restrict__ plut) {
    const int tid = threadIdx.x;
    const int blk = blockIdx.x;                  // node
    const int lane = tid & 63, wave = tid >> 6;  // 16 waves x 64 lanes = 1024 entries
    int v = lut[(size_t)blk * 1024 + tid];
    uint64_t m = __ballot(v & 1);
    if (lane == 0) plut[(size_t)blk * 16 + wave] = m;
}

// ---------------- one reservoir step ----------------
__global__ __launch_bounds__(STEP_THREADS)
void step_kernel(const uint8_t* __restrict__ plut,
                 const int* __restrict__ adjoffT,      // [10][N_NODES]
                 const int* __restrict__ jmv,          // [N_NODES]
                 const uint64_t* __restrict__ xmask,   // [32][64]
                 const uint64_t* __restrict__ src,
                 uint64_t* __restrict__ dst,
                 int t) {
    __shared__ uint8_t lutb[NODES_PER_WG * 128];   // 8 KB packed LUT rows
    const int tid = threadIdx.x;
    const int wg  = blockIdx.x;

    // 1) issue LUT staging loads first (32 B/thread, coalesced)
    size_t sb = (size_t)wg * (NODES_PER_WG * 128) + (size_t)tid * 32;
    uint4 s0 = make_uint4(0, 0, 0, 0), s1 = s0;
    if (sb + 32 <= (size_t)N_NODES * 128) {
        const uint4* ps = (const uint4*)(plut + sb);
        s0 = ps[0]; s1 = ps[1];
    }

    const int nl = tid >> 2, q = tid & 3;          // node-local, batch quarter
    const int node = wg * NODES_PER_WG + nl;
    const bool valid = node < N_NODES;

    // 2) issue the 10 random state gathers (in flight during staging)
    uint32_t w[K_MAX];
    int j = -1;
    if (valid) {
        j = jmv[node];
        #pragma unroll
        for (int k = 0; k < K_MAX; ++k) {
            uint32_t off = (uint32_t)adjoffT[k * N_NODES + node] + (uint32_t)(q * 2);
            w[k] = *(const uint16_t*)((const char*)src + off);
        }
    }

    // 3) LDS staging (waits only the staging loads), barrier
    ((uint4*)lutb)[tid * 2]     = s0;
    ((uint4*)lutb)[tid * 2 + 1] = s1;
    __syncthreads();

    if (!valid) return;
    const int rowbase = nl * 128;
    uint32_t o16 = 0;
    #pragma unroll
    for (int b = 0; b < 16; ++b) {
        uint32_t idx = 0;
        #pragma unroll
        for (int k = 0; k < K_MAX; ++k)
            idx |= ((w[k] >> b) & 1u) << (9 - k);       // pow2[k] = 2^(9-k)
        uint32_t byte = lutb[rowbase + (idx >> 3)];
        o16 |= ((byte >> (idx & 7)) & 1u) << b;
    }
    // fold next step's input-bit XOR into this write
    if (j >= 0 && t < T_STEPS - 1)
        o16 ^= (uint32_t)((xmask[(t + 1) * INPUT_BITS + j] >> (q * 16)) & 0xFFFFu);

    ((uint16_t*)dst)[(size_t)node * 4 + q] = (uint16_t)o16;
}

// ---------------- output: out[b,i] = sum_n state[b,n]*W[i,n] + bias[i] ----------------
__global__ void out_kernel(const uint64_t* __restrict__ fstate,
                           const float* __restrict__ W,
                           const float* __restrict__ bias,
                           float* __restrict__ out) {
    const int wg = blockIdx.x;          // b*16 + i
    const int b = wg >> 4, i = wg & 15;
    const int tid = threadIdx.x;
    const uint8_t* st = (const uint8_t*)fstate;
    const int byteoff = b >> 3, bsh = b & 7;

    float s = 0.f;
    for (int n = tid; n < N_NODES; n += 256) {
        uint32_t bit = (st[(size_t)n * 8 + byteoff] >> bsh) & 1u;
        s += (float)bit * W[(size_t)i * N_NODES + n];
    }
    #pragma unroll
    for (int off = 32; off; off >>= 1) s += __shfl_down(s, off);

    __shared__ float part[4];
    const int lane = tid & 63, wave = tid >> 6;
    if (lane == 0) part[wave] = s;
    __syncthreads();
    if (tid == 0) out[wg] = part[0] + part[1] + part[2] + part[3] + bias[i];
}

extern "C" void kernel_launch(void* const* d_in, const int* in_sizes, int n_in,
                              void* d_out, int out_size, void* d_ws, size_t ws_size,
                              hipStream_t stream) {
    const int*   x       = (const int*)d_in[0];
    const int*   adj     = (const int*)d_in[1];
    const int*   adjmask = (const int*)d_in[2];
    const int*   lut     = (const int*)d_in[3];
    const int*   initst  = (const int*)d_in[4];
    const int*   innodes = (const int*)d_in[5];
    const float* W       = (const float*)d_in[6];
    const float* bias    = (const float*)d_in[7];
    float* out = (float*)d_out;

    char* ws = (char*)d_ws;
    uint64_t* buf0    = (uint64_t*)(ws + OFF_BUF0);
    uint64_t* buf1    = (uint64_t*)(ws + OFF_BUF1);
    uint64_t* xmask   = (uint64_t*)(ws + OFF_XMASK);
    int*      jmv     = (int*)     (ws + OFF_JM);
    int*      adjoffT = (int*)     (ws + OFF_ADJ);
    uint64_t* plut    = (uint64_t*)(ws + OFF_PLUT);

    {
        int prep_threads = (N_NODES + 1) + T_STEPS * INPUT_BITS;
        int prep_blocks = (prep_threads + 255) / 256;
        hipLaunchKernelGGL(prep_kernel, dim3(prep_blocks), dim3(256), 0, stream,
                           x, adj, adjmask, initst, innodes,
                           buf0, buf1, xmask, jmv, adjoffT);
    }

    hipLaunchKernelGGL(lutpack_kernel, dim3(N_NODES), dim3(1024), 0, stream, lut, plut);

    for (int t = 0; t < T_STEPS; ++t) {
        uint64_t* src = (t & 1) ? buf1 : buf0;
        uint64_t* dst = (t & 1) ? buf0 : buf1;
        hipLaunchKernelGGL(step_kernel, dim3(STEP_WGS), dim3(STEP_THREADS), 0, stream,
                           (const uint8_t*)plut, adjoffT, jmv, xmask,
                           (const uint64_t*)src, dst, t);
    }

    // after 32 steps the final states live in buf0 (32 is even)
    hipLaunchKernelGGL(out_kernel, dim3(BATCH * N_INPUTS), dim3(256), 0, stream,
                       (const uint64_t*)buf0, W, bias, out);
}